// Round 4
// baseline (171.417 us; speedup 1.0000x reference)
//
#include <hip/hip_runtime.h>

#define IN_F 8192
#define OUT_F 8192
#define N4 (IN_F / 4)          // 2048 float4 per row
#define BLOCK 256

typedef float v4f __attribute__((ext_vector_type(4)));

// ---------------- Kernel A: masked GEMV + LIF update ----------------
// One block per output row. 2048 float4 / 256 threads = 8 float4 per thread,
// fully unrolled -> 8 loads in flight. Pure read stream (256 MB).
__global__ __launch_bounds__(BLOCK) void snn_gemv_kernel(
    const float* __restrict__ x,        // [IN_F]
    const float* __restrict__ syn,      // [OUT_F, IN_F]
    const float* __restrict__ mp,       // [OUT_F]
    const float* __restrict__ at,       // [OUT_F]
    float* __restrict__ spikes_out,     // [OUT_F]
    float* __restrict__ vmem_out,       // [OUT_F]
    float* __restrict__ thr_out)        // [OUT_F]
{
    const int o   = blockIdx.x;
    const int tid = threadIdx.x;

    const v4f* __restrict__ syn4 = reinterpret_cast<const v4f*>(syn + (size_t)o * IN_F);
    const v4f* __restrict__ x4   = reinterpret_cast<const v4f*>(x);

    float partial = 0.0f;
    #pragma unroll
    for (int k = 0; k < N4 / BLOCK; ++k) {          // 8 iterations, fully unrolled
        const int i = tid + k * BLOCK;
        v4f s  = syn4[i];
        v4f xv = x4[i];
        partial += (s.x > 50.0f ? xv.x : 0.0f);
        partial += (s.y > 50.0f ? xv.y : 0.0f);
        partial += (s.z > 50.0f ? xv.z : 0.0f);
        partial += (s.w > 50.0f ? xv.w : 0.0f);
    }

    // wave reduce (64 lanes), then cross-wave via LDS
    #pragma unroll
    for (int off = 32; off > 0; off >>= 1)
        partial += __shfl_down(partial, off, 64);

    __shared__ float wsum[BLOCK / 64];
    if ((tid & 63) == 0) wsum[tid >> 6] = partial;
    __syncthreads();

    if (tid == 0) {
        float cur = wsum[0] + wsum[1] + wsum[2] + wsum[3];
        float v   = mp[o] * 0.8f + cur;
        float a   = at[o];
        float sp  = (v >= a) ? 1.0f : 0.0f;
        spikes_out[o] = sp;
        vmem_out[o]   = v * (1.0f - sp) * 0.2f;
        thr_out[o]    = fminf(fmaxf(a + (sp - 0.05f) * 0.1f, 0.5f), 10.0f);
    }
}

// ---------------- Kernel B: trace update (pure stream) ----------------
// Flat grid-stride over all 16M float4 elements. No barriers, no row phases.
// trace_out = clip(0.7*trace + 3*spike[row]*x[col], 0, 10)
#define B_GRID 2048
#define B_THREADS ((size_t)B_GRID * BLOCK)          // 524288
#define B_ITERS ((size_t)OUT_F * N4 / B_THREADS)    // 32

__global__ __launch_bounds__(BLOCK) void snn_trace_kernel(
    const float* __restrict__ x,          // [IN_F]
    const float* __restrict__ trace,      // [OUT_F, IN_F]
    const float* __restrict__ spikes,     // [OUT_F] (written by kernel A)
    float* __restrict__ trace_out)        // [OUT_F, IN_F]
{
    const size_t g0 = (size_t)blockIdx.x * BLOCK + threadIdx.x;

    const v4f* __restrict__ tr4 = reinterpret_cast<const v4f*>(trace);
    const v4f* __restrict__ x4  = reinterpret_cast<const v4f*>(x);
    v4f* __restrict__ out4      = reinterpret_cast<v4f*>(trace_out);

    #pragma unroll 8
    for (size_t k = 0; k < B_ITERS; ++k) {
        const size_t g = g0 + k * B_THREADS;
        v4f t   = tr4[g];
        v4f xv  = x4[g & (N4 - 1)];                 // col (L2-resident, 32 KB)
        float s3 = spikes[g >> 11] * 3.0f;          // row = g / 2048 (L1-resident)
        v4f r;
        r.x = fminf(fmaxf(t.x * 0.7f + s3 * xv.x, 0.0f), 10.0f);
        r.y = fminf(fmaxf(t.y * 0.7f + s3 * xv.y, 0.0f), 10.0f);
        r.z = fminf(fmaxf(t.z * 0.7f + s3 * xv.z, 0.0f), 10.0f);
        r.w = fminf(fmaxf(t.w * 0.7f + s3 * xv.w, 0.0f), 10.0f);
        out4[g] = r;
    }
}

extern "C" void kernel_launch(void* const* d_in, const int* in_sizes, int n_in,
                              void* d_out, int out_size, void* d_ws, size_t ws_size,
                              hipStream_t stream) {
    const float* x     = (const float*)d_in[0];  // spike_input [8192]
    const float* syn   = (const float*)d_in[1];  // synapse_states [8192,8192]
    const float* mp    = (const float*)d_in[2];  // membrane_potential [8192]
    const float* at    = (const float*)d_in[3];  // adaptive_threshold [8192]
    const float* trace = (const float*)d_in[4];  // eligibility_trace [8192,8192]

    float* out        = (float*)d_out;
    float* spikes_out = out;                                            // [8192]
    float* vmem_out   = out + OUT_F;                                    // [8192]
    float* trace_out  = out + 2 * (size_t)OUT_F;                        // [8192*8192]
    float* thr_out    = out + 2 * (size_t)OUT_F + (size_t)OUT_F * IN_F; // [8192]

    snn_gemv_kernel<<<OUT_F, BLOCK, 0, stream>>>(
        x, syn, mp, at, spikes_out, vmem_out, thr_out);

    snn_trace_kernel<<<B_GRID, BLOCK, 0, stream>>>(
        x, trace, spikes_out, trace_out);
}

// Round 5
// 141.387 us; speedup vs baseline: 1.2124x; 1.2124x over previous
//
#include <hip/hip_runtime.h>

#define IN_F 8192
#define OUT_F 8192
#define BLOCK 256
#define KPT (IN_F / 4 / BLOCK)   // 8 float4 per thread per stream

typedef float v4f __attribute__((ext_vector_type(4)));

// Fused, fully register-staged: one block per output row.
// All reads (syn row, trace row, x) issue up-front into registers (24
// independent 16B loads in flight per thread); masked row-sum consumes syn;
// after the reduce, phase 2 is pure register->HBM writes. No load is ever
// gated behind the reduce barrier.
__global__ __launch_bounds__(BLOCK, 4) void snn_fused_kernel(
    const float* __restrict__ x,        // [IN_F] spike_input
    const float* __restrict__ syn,      // [OUT_F, IN_F] synapse_states
    const float* __restrict__ mp,       // [OUT_F] membrane_potential
    const float* __restrict__ at,       // [OUT_F] adaptive_threshold
    const float* __restrict__ trace,    // [OUT_F, IN_F] eligibility_trace
    float* __restrict__ spikes_out,     // [OUT_F]
    float* __restrict__ vmem_out,       // [OUT_F]
    float* __restrict__ trace_out,      // [OUT_F, IN_F]
    float* __restrict__ thr_out)        // [OUT_F]
{
    const int o   = blockIdx.x;
    const int tid = threadIdx.x;

    const v4f* __restrict__ syn4 = reinterpret_cast<const v4f*>(syn + (size_t)o * IN_F);
    const v4f* __restrict__ tr4  = reinterpret_cast<const v4f*>(trace + (size_t)o * IN_F);
    const v4f* __restrict__ x4   = reinterpret_cast<const v4f*>(x);

    // ---- issue ALL loads up front (static indices -> registers, no scratch)
    v4f t[KPT], s[KPT], xv[KPT];
    #pragma unroll
    for (int k = 0; k < KPT; ++k) t[k] = tr4[tid + k * BLOCK];     // HBM stream
    #pragma unroll
    for (int k = 0; k < KPT; ++k) s[k] = syn4[tid + k * BLOCK];    // HBM stream
    #pragma unroll
    for (int k = 0; k < KPT; ++k) xv[k] = x4[tid + k * BLOCK];     // L1/L2-resident

    // ---- masked row-sum: current[o] = sum_i (syn[o,i] > 50) * x[i]
    float partial = 0.0f;
    #pragma unroll
    for (int k = 0; k < KPT; ++k) {
        partial += (s[k].x > 50.0f ? xv[k].x : 0.0f);
        partial += (s[k].y > 50.0f ? xv[k].y : 0.0f);
        partial += (s[k].z > 50.0f ? xv[k].z : 0.0f);
        partial += (s[k].w > 50.0f ? xv[k].w : 0.0f);
    }

    // wave reduce, then cross-wave via LDS
    #pragma unroll
    for (int off = 32; off > 0; off >>= 1)
        partial += __shfl_down(partial, off, 64);

    __shared__ float wsum[BLOCK / 64];
    __shared__ float s_sp;
    if ((tid & 63) == 0) wsum[tid >> 6] = partial;
    __syncthreads();

    if (tid == 0) {
        float cur = wsum[0] + wsum[1] + wsum[2] + wsum[3];
        float v   = mp[o] * 0.8f + cur;
        float a   = at[o];
        float sp  = (v >= a) ? 1.0f : 0.0f;
        spikes_out[o] = sp;
        vmem_out[o]   = v * (1.0f - sp) * 0.2f;
        thr_out[o]    = fminf(fmaxf(a + (sp - 0.05f) * 0.1f, 0.5f), 10.0f);
        s_sp = sp;
    }
    __syncthreads();

    // ---- phase 2: pure register->HBM write burst
    const float sp3 = s_sp * 3.0f;
    v4f* out4 = reinterpret_cast<v4f*>(trace_out + (size_t)o * IN_F);

    #pragma unroll
    for (int k = 0; k < KPT; ++k) {
        v4f r;
        r.x = fminf(fmaxf(t[k].x * 0.7f + sp3 * xv[k].x, 0.0f), 10.0f);
        r.y = fminf(fmaxf(t[k].y * 0.7f + sp3 * xv[k].y, 0.0f), 10.0f);
        r.z = fminf(fmaxf(t[k].z * 0.7f + sp3 * xv[k].z, 0.0f), 10.0f);
        r.w = fminf(fmaxf(t[k].w * 0.7f + sp3 * xv[k].w, 0.0f), 10.0f);
        out4[tid + k * BLOCK] = r;
    }
}

extern "C" void kernel_launch(void* const* d_in, const int* in_sizes, int n_in,
                              void* d_out, int out_size, void* d_ws, size_t ws_size,
                              hipStream_t stream) {
    const float* x     = (const float*)d_in[0];  // spike_input [8192]
    const float* syn   = (const float*)d_in[1];  // synapse_states [8192,8192]
    const float* mp    = (const float*)d_in[2];  // membrane_potential [8192]
    const float* at    = (const float*)d_in[3];  // adaptive_threshold [8192]
    const float* trace = (const float*)d_in[4];  // eligibility_trace [8192,8192]

    float* out        = (float*)d_out;
    float* spikes_out = out;                                            // [8192]
    float* vmem_out   = out + OUT_F;                                    // [8192]
    float* trace_out  = out + 2 * (size_t)OUT_F;                        // [8192*8192]
    float* thr_out    = out + 2 * (size_t)OUT_F + (size_t)OUT_F * IN_F; // [8192]

    snn_fused_kernel<<<OUT_F, BLOCK, 0, stream>>>(
        x, syn, mp, at, trace, spikes_out, vmem_out, trace_out, thr_out);
}